// Round 11
// baseline (4110.504 us; speedup 1.0000x reference)
//
#include <hip/hip_runtime.h>

#define KP   2176
#define H    2048
#define IN   69
#define TGT  50
#define NKT  68     // K-tiles of 32 (2048 h + 69 x + pad)

typedef unsigned short ushort_t;
typedef unsigned int   uint_t;
typedef __attribute__((ext_vector_type(8))) short  short8;
typedef __attribute__((ext_vector_type(4))) float  float4_t;

#define MFMA_BF16 __builtin_amdgcn_mfma_f32_16x16x32_bf16

__device__ __forceinline__ ushort_t f2bf(float f) {
  union { float f; unsigned u; } v; v.f = f;
  unsigned u = v.u;
  return (ushort_t)((u + 0x7fffu + ((u >> 16) & 1u)) >> 16);
}

template <int N> __device__ __forceinline__ void waitv() {
  asm volatile("s_waitcnt vmcnt(%0)" :: "n"(N) : "memory");
}
#define LGKM0() asm volatile("s_waitcnt lgkmcnt(0)" ::: "memory")
#define SGB0()  __builtin_amdgcn_sched_barrier(0)
#define FENCE() asm volatile("" ::: "memory")

// plain load; base MUST be wave-uniform (SGPR pair), per-thread offset goes in voff.
template <int OFF> __device__ __forceinline__ void gld(short8& d, uint_t voff, const void* base) {
  asm volatile("global_load_dwordx4 %0, %1, %2 offset:%3"
               : "=v"(d) : "v"(voff), "s"(base), "n"(OFF));
}

// ================= fragment-major layouts (r7/r10-proven) =================
// W3[rb 0..383][kt 0..67][lane][16B], rb = cb*3 + g (cb = 16-col block, g = gate):
//   col c = cb*16 + (lane&15); fused row = [W_hh[g*2048+c] (k<2048) | W_ih[...] | 0]
// A2[mb 0..31][kt 0..67][lane][16B]: lane&15 -> m-row, lane>>4 -> k-quarter.
// F2[kt 0..63][nf 0..4][lane][16B]: fc1 cols j = nf*16 + (lane&15).

__global__ void build_w3(const float* __restrict__ Whh, const float* __restrict__ Wih,
                         ushort_t* __restrict__ W3) {
  int i = blockIdx.x * 256 + threadIdx.x;   // 6528*256 = 1,671,168 = 384*68*64
  int lane = i & 63;
  int kt = (i >> 6) % NKT;
  int rb = i / (64 * NKT);                  // 0..383
  int cb = rb / 3, g = rb - cb * 3;
  int c  = cb * 16 + (lane & 15);
  int gr = g * H + c;
  int k0 = kt * 32 + (lane >> 4) * 8;
  short8 v;
  #pragma unroll
  for (int j = 0; j < 8; ++j) {
    int k = k0 + j;
    float val = 0.f;
    if (k < H) val = Whh[(size_t)gr * H + k];
    else if (k < H + IN) val = Wih[(size_t)gr * IN + (k - H)];
    v[j] = (short)f2bf(val);
  }
  *(short8*)(W3 + (size_t)i * 8) = v;
}

__global__ void build_f2(const float* __restrict__ fc1w, ushort_t* __restrict__ F2) {
  int i = blockIdx.x * 256 + threadIdx.x;   // 80*256 = 20480 = 64*5*64
  int lane = i & 63;
  int ni = (i >> 6) % 5;
  int kt = i / 320;
  int j  = ni * 16 + (lane & 15);
  int k0 = kt * 32 + (lane >> 4) * 8;
  short8 v;
  #pragma unroll
  for (int jj = 0; jj < 8; ++jj) {
    float val = (j < IN) ? fc1w[(size_t)j * H + k0 + jj] : 0.f;
    v[jj] = (short)f2bf(val);
  }
  *(short8*)(F2 + (size_t)i * 8) = v;
}

__global__ void zero_u4(uint4* p, int n) {
  int i = blockIdx.x * 256 + threadIdx.x;
  if (i < n) p[i] = make_uint4(0, 0, 0, 0);
}

__device__ __forceinline__ size_t a2_x_off(int b, int j) {
  int k = 2048 + j;
  int kt = k >> 5, kk = k & 31;
  int mb = b >> 4;
  int ln = (b & 15) | ((kk >> 3) << 4);
  return ((size_t)(mb * NKT + kt) * 64 + ln) * 16 + (kk & 7) * 2;
}

__global__ void fill_x0(const float* __restrict__ enc, char* __restrict__ A2) {
  int i = blockIdx.x * 256 + threadIdx.x;   // 512*69
  int b = i / IN, j = i - b * IN;
  *(ushort_t*)(A2 + a2_x_off(b, j)) = f2bf(enc[(size_t)b * 100 * IN + j]);
}

// ================= fused GRU step (r11: 2 WGs/CU for TLP) =================
// grid 512: xcd = bid&7, slot = bid>>3; cg = xcd*8 + (slot&7) (0..63, 32 cols/WG,
// kt == cg for writeback), mt = slot>>3 (BM=64). 2 WGs/CU -> 8 waves/CU (2/SIMD).
// Wave w: wc = w&1 -> cb = cg*2+wc (16 cols x 3 gates; wave-pair shares B via L1);
// wh = w>>1 -> m-half (mb blocks mt*4+2wh, +1). A deduped via 4-slot LDS relay
// (wave w stages chunk w). Every wave: exactly 4 loads/tile -> r10's verified
// queue math unchanged (prologue 25 loads, waitv<24>; steady waitv<15>).
__global__ __launch_bounds__(256, 1) void gru_step(
    const char* __restrict__ Aprev, char* __restrict__ Anext,
    const char* __restrict__ W3p, float* __restrict__ h32,
    const float* __restrict__ bih, const float* __restrict__ bhh,
    const float* __restrict__ xsrc, int xstride)
{
  __shared__ short8  Aring[4][4][64];      // 16KB ring: [slot][chunk mi][lane]
  __shared__ ushort_t smh[64][36];         // 4.5KB epilogue transpose (72B row stride)

  const int tid = threadIdx.x;
  const int bid = blockIdx.x;
  const int lane = tid & 63, w = tid >> 6;
  const int l15 = lane & 15, l4 = lane >> 4;
  const int slot = bid >> 3;
  const int cg = (bid & 7) * 8 + (slot & 7);   // 0..63
  const int mt = slot >> 3;                    // 0..7
  const int wc = w & 1, wh = w >> 1;
  const int cb = cg * 2 + wc;                  // 0..127
  const int c  = cb * 16 + l15;

  const float br  = bih[c] + bhh[c];
  const float bz  = bih[H + c] + bhh[H + c];
  const float bin = bih[2 * H + c];
  const float bhn = bhh[2 * H + c];
  // pin biases into regs: no compiler vmem outstanding during the counted pipeline
  asm volatile("" :: "v"(br), "v"(bz), "v"(bin), "v"(bhn));

  const void* ApW = Aprev + (size_t)(mt * 4) * (NKT * 1024);      // wave-uniform base
  uint_t vA  = (uint_t)(w * (NKT * 1024) + lane * 16);            // wave chunk via voffset
  uint_t vB0 = (uint_t)((cb * 3 + 0) * (NKT * 1024) + lane * 16);
  uint_t vB1 = (uint_t)((cb * 3 + 1) * (NKT * 1024) + lane * 16);
  uint_t vB2 = (uint_t)((cb * 3 + 2) * (NKT * 1024) + lane * 16);

  short8 sa[4], fb[8][3];
  short8 fa0, fa1;
  float4_t acc[2][4] = {};   // [mi][r, z, gh_n, gi_n]

#define AISS(sl) { gld<0>(sa[sl], vA, ApW); vA += 1024; }
#define BISS(sl) { gld<0>(fb[sl][0], vB0, W3p); gld<0>(fb[sl][1], vB1, W3p); \
                   gld<0>(fb[sl][2], vB2, W3p); vB0 += 1024; vB1 += 1024; vB2 += 1024; }
#define MFMA3(mi, fav, j, G2) \
  acc[mi][0]  = MFMA_BF16(fav, fb[j][0], acc[mi][0], 0, 0, 0); \
  acc[mi][1]  = MFMA_BF16(fav, fb[j][1], acc[mi][1], 0, 0, 0); \
  acc[mi][G2] = MFMA_BF16(fav, fb[j][2], acc[mi][G2], 0, 0, 0);
#define MFMA6(j, G2) MFMA3(0, fa0, j, G2) MFMA3(1, fa1, j, G2)
#define RDFA(ss) \
  FENCE(); \
  fa0 = Aring[ss][wh * 2][lane]; fa1 = Aring[ss][wh * 2 + 1][lane];

// steady tile j (u=j&7): issue A(j+4) into sa[j&3], B(j+7) into fb[(u+7)&7] (the slot
// consumed this tile, u&7, is never redefined before its MFMA — no dead SSA, no WAR);
// waitv<15> retires exactly A(j+1); relay-write it; barrier; read A(j) frags; MFMA.
#define GRUT(u, G2) \
  AISS((u + 4) & 3) BISS((u + 7) & 7) \
  waitv<15>(); SGB0(); \
  Aring[(u + 1) & 3][w][lane] = sa[(u + 1) & 3]; \
  LGKM0(); \
  __builtin_amdgcn_s_barrier(); \
  RDFA(u & 3) \
  LGKM0(); SGB0(); \
  MFMA6(u, G2)

// tail: A-issue only (tiles 61..63)
#define GRUTA(u, NW) \
  AISS((u + 4) & 3) \
  waitv<NW>(); SGB0(); \
  Aring[(u + 1) & 3][w][lane] = sa[(u + 1) & 3]; \
  LGKM0(); \
  __builtin_amdgcn_s_barrier(); \
  RDFA(u & 3) \
  LGKM0(); SGB0(); \
  MFMA6(u, 2)

// tail: no issue, with/without relay-write (tiles 64..67)
#define GRUTN_W(u, NW, G2) \
  waitv<NW>(); SGB0(); \
  Aring[(u + 1) & 3][w][lane] = sa[(u + 1) & 3]; \
  LGKM0(); \
  __builtin_amdgcn_s_barrier(); \
  RDFA(u & 3) \
  LGKM0(); SGB0(); \
  MFMA6(u, G2)
#define GRUTN_NW(u, NW, G2) \
  waitv<NW>(); SGB0(); \
  LGKM0(); \
  __builtin_amdgcn_s_barrier(); \
  RDFA(u & 3) \
  LGKM0(); SGB0(); \
  MFMA6(u, G2)

  // ---- prologue: A0..A3 + B0..B6 in flight (25 loads); pre-relay A0 ----
  AISS(0) AISS(1) AISS(2) AISS(3)
  BISS(0) BISS(1) BISS(2) BISS(3) BISS(4) BISS(5) BISS(6)
  waitv<24>(); SGB0();                 // retire exactly A0
  Aring[0][w][lane] = sa[0];
  LGKM0();
  __builtin_amdgcn_s_barrier();

  // ---- steady: tiles 0..55 ----
  #pragma unroll 1
  for (int g8 = 0; g8 < 7; ++g8) {
    GRUT(0, 2) GRUT(1, 2) GRUT(2, 2) GRUT(3, 2)
    GRUT(4, 2) GRUT(5, 2) GRUT(6, 2) GRUT(7, 2)
  }
  // tiles 56..60 (full issues: A60..64, B63..67)
  GRUT(0, 2) GRUT(1, 2) GRUT(2, 2) GRUT(3, 2) GRUT(4, 2)
  // tiles 61..63 (A65..67 issues only; descending waits keep exact accounting)
  GRUTA(5, 12) GRUTA(6, 9) GRUTA(7, 6)
  // tiles 64..67: x-part -> gi_n (G2=3); drain exactly to 0; no issues
  GRUTN_W(0, 2, 3) GRUTN_W(1, 1, 3) GRUTN_W(2, 0, 3) GRUTN_NW(3, 0, 3)
  // vmcnt == 0 and lgkm == 0: nothing outstanding can clobber reused registers.

  // ---- epilogue: gates fp32, fp32 carry; h' -> LDS transpose -> 16B stores ----
  #pragma unroll
  for (int mi = 0; mi < 2; ++mi) {
    #pragma unroll
    for (int r4 = 0; r4 < 4; ++r4) {
      int mloc = (wh * 2 + mi) * 16 + l4 * 4 + r4;     // 0..63 within WG
      int m = mt * 64 + mloc;
      float rg = 1.f / (1.f + __expf(-(acc[mi][0][r4] + br)));
      float zg = 1.f / (1.f + __expf(-(acc[mi][1][r4] + bz)));
      float ng = tanhf(acc[mi][3][r4] + bin + rg * (acc[mi][2][r4] + bhn));
      float hold = h32[(size_t)m * H + c];
      float hn = (1.f - zg) * ng + zg * hold;
      h32[(size_t)m * H + c] = hn;
      smh[mloc][wc * 16 + l15] = f2bf(hn);
    }
  }
  __syncthreads();
  // 256 chunks of 16B: this WG's 64 rows x 32 cols land in kt == cg exactly.
  {
    int mloc = tid >> 2, khi = tid & 3;
    short8 v = *(const short8*)&smh[mloc][khi * 8];
    int m_abs = mt * 64 + mloc;
    int mb2 = m_abs >> 4;
    int ln = (m_abs & 15) | (khi << 4);
    *(short8*)(Anext + ((size_t)(mb2 * NKT + cg) * 64 + ln) * 16) = v;
  }
  // encoder next-x feed (cg==0: 8 WGs, mt 0..7 cover all 512 rows)
  if (cg == 0 && xsrc != nullptr) {
    for (int i = tid; i < 64 * IN; i += 256) {
      int rr = i / IN, cc = i - rr * IN;
      int m = mt * 64 + rr;
      *(ushort_t*)(Anext + a2_x_off(m, cc)) = f2bf(xsrc[(size_t)m * xstride + cc]);
    }
  }
}

// ================= decoder output step (r7-proven, unchanged) =================
__global__ __launch_bounds__(256, 1) void out_step(
    char* __restrict__ Acat, const char* __restrict__ F2p,
    const float* __restrict__ fc1b, const float* __restrict__ inp,
    float* __restrict__ outp)
{
  __shared__ float4_t redf[4 * 5 * 64];    // 20KB
  const int tid = threadIdx.x;
  const int mb = blockIdx.x;               // 0..31
  const int lane = tid & 63, w = tid >> 6;
  const int l15 = lane & 15, l4 = lane >> 4;

  const void* F2b = (const char*)F2p + 4096;   // imm offset max 4095 -> second base
  uint_t voA = (uint_t)((mb * NKT + w * 16) * 1024 + lane * 16);
  uint_t vf  = (uint_t)((w * 16) * 5120 + lane * 16);

  short8 da[8], db[8][5];
  float4_t oa[5] = {};

#define DPRO(sl) \
  gld<0>(da[sl], voA, Acat); \
  gld<0>(db[sl][0], vf, F2p); gld<1024>(db[sl][1], vf, F2p); \
  gld<2048>(db[sl][2], vf, F2p); gld<3072>(db[sl][3], vf, F2p); \
  gld<0>(db[sl][4], vf, F2b); \
  voA += 1024; vf += 5120;
#define DMM(sl) \
  { _Pragma("unroll") for (int nf = 0; nf < 5; ++nf) \
      oa[nf] = MFMA_BF16(da[sl], db[sl][nf], oa[nf], 0, 0, 0); }

  DPRO(0) DPRO(1) DPRO(2) DPRO(3) DPRO(4) DPRO(5) DPRO(6) DPRO(7)
  waitv<42>(); SGB0(); DMM(0) DPRO(0)
  waitv<42>(); SGB0(); DMM(1) DPRO(1)
  waitv<42>(); SGB0(); DMM(2) DPRO(2)
  waitv<42>(); SGB0(); DMM(3) DPRO(3)
  waitv<42>(); SGB0(); DMM(4) DPRO(4)
  waitv<42>(); SGB0(); DMM(5) DPRO(5)
  waitv<42>(); SGB0(); DMM(6) DPRO(6)
  waitv<42>(); SGB0(); DMM(7) DPRO(7)
  waitv<42>(); SGB0(); DMM(0)
  waitv<36>(); SGB0(); DMM(1)
  waitv<30>(); SGB0(); DMM(2)
  waitv<24>(); SGB0(); DMM(3)
  waitv<18>(); SGB0(); DMM(4)
  waitv<12>(); SGB0(); DMM(5)
  waitv<6>();  SGB0(); DMM(6)
  waitv<0>();  SGB0(); DMM(7)
  // vmcnt == 0: pipeline fully drained before register reuse below.

  #pragma unroll
  for (int nf = 0; nf < 5; ++nf) redf[(w * 5 + nf) * 64 + lane] = oa[nf];
  __syncthreads();

  #pragma unroll 1
  for (int pass = 0; pass < 2; ++pass) {
    if (pass == 1 && w != 0) break;
    const int nf = pass ? 4 : w;
    float4_t sum = redf[(0 * 5 + nf) * 64 + lane] + redf[(1 * 5 + nf) * 64 + lane]
                 + redf[(2 * 5 + nf) * 64 + lane] + redf[(3 * 5 + nf) * 64 + lane];
    int j = nf * 16 + l15;
    if (j < IN) {
      float bj = fc1b[j];
      #pragma unroll
      for (int r4 = 0; r4 < 4; ++r4) {
        int m = mb * 16 + l4 * 4 + r4;
        float v = sum[r4] + bj + inp[(size_t)m * (TGT * IN) + j];
        outp[(size_t)m * (TGT * IN) + j] = v;
        *(ushort_t*)(Acat + a2_x_off(m, j)) = f2bf(v);   // next decoder input
      }
    }
  }
}

// ================= launch =================
extern "C" void kernel_launch(void* const* d_in, const int* in_sizes, int n_in,
                              void* d_out, int out_size, void* d_ws, size_t ws_size,
                              hipStream_t stream) {
  const float* enc  = (const float*)d_in[0];
  const float* dec  = (const float*)d_in[1];
  const float* Wih  = (const float*)d_in[2];
  const float* Whh  = (const float*)d_in[3];
  const float* b_ih = (const float*)d_in[4];
  const float* b_hh = (const float*)d_in[5];
  const float* fc1w = (const float*)d_in[6];
  const float* fc1b = (const float*)d_in[7];
  float* out = (float*)d_out;

  char* ws = (char*)d_ws;
  ushort_t* W3  = (ushort_t*)ws;                    // 384*68*64*16 = 26,738,688
  char*     A0  = ws + 26738688;                    // 2,228,224
  char*     A1  = ws + 28966912;                    // 2,228,224
  float*    h32 = (float*)(ws + 31195136);          // 4,194,304
  ushort_t* F2  = (ushort_t*)(ws + 35389440);       // 327,680
  char* A2[2] = {A0, A1};

  build_w3<<<6528, 256, 0, stream>>>(Whh, Wih, W3);
  zero_u4<<<2112, 256, 0, stream>>>((uint4*)A0, 540672);   // A0 + A1 + h32
  fill_x0<<<138, 256, 0, stream>>>(enc, A0);
  build_f2<<<80, 256, 0, stream>>>(fc1w, F2);

  for (int t = 0; t < 149; ++t) {
    const float* xsrc = nullptr; int xstride = 0;
    if (t < 98)       { xsrc = enc + (size_t)(t + 1) * IN; xstride = 100 * IN; }
    else if (t == 98) { xsrc = dec;                        xstride = TGT * IN; }
    gru_step<<<512, 256, 0, stream>>>(A2[t & 1], A2[(t + 1) & 1], (const char*)W3, h32,
                                      b_ih, b_hh, xsrc, xstride);
    if (t >= 99) {
      int d = t - 99;
      const float* inp = (d == 0) ? dec : out + (size_t)(d - 1) * IN;
      out_step<<<32, 256, 0, stream>>>(A2[(t + 1) & 1], (const char*)F2, fc1b, inp,
                                       out + (size_t)d * IN);
    }
  }
}